// Round 4
// baseline (344.874 us; speedup 1.0000x reference)
//
#include <hip/hip_runtime.h>

typedef unsigned short u16;
typedef __attribute__((ext_vector_type(8))) short short8;
typedef __attribute__((ext_vector_type(4))) float f32x4;
typedef __attribute__((ext_vector_type(4))) unsigned int u32x4;

union V8 { u32x4 u; short8 s; };

// ---------- helpers ----------
__device__ __forceinline__ u16 f2bf(float f) {
  union { float f; unsigned u; } v; v.f = f;
  unsigned r = v.u + 0x7fffu + ((v.u >> 16) & 1u);   // RNE
  return (u16)(r >> 16);
}

__device__ __forceinline__ unsigned cvt_pk_bf16(float lo, float hi) {
  unsigned r;
  asm("v_cvt_pk_bf16_f32 %0, %1, %2" : "=v"(r) : "v"(lo), "v"(hi));
  return r;
}

__device__ __forceinline__ void gload_lds16(const void* g, void* l) {
  __builtin_amdgcn_global_load_lds((const __attribute__((address_space(1))) unsigned int*)g,
                                   (__attribute__((address_space(3))) unsigned int*)l, 16, 0, 0);
}

__device__ __forceinline__ f32x4 mfma16(short8 a, short8 b, f32x4 c) {
  return __builtin_amdgcn_mfma_f32_16x16x32_bf16(a, b, c, 0, 0, 0);
}

// ---------- f32 -> bf16 convert, 3 tensors fused ----------
__global__ __launch_bounds__(256) void cvt3_kernel(const float* __restrict__ q,
                                                   const float* __restrict__ k,
                                                   const float* __restrict__ v,
                                                   u16* __restrict__ oq,
                                                   u16* __restrict__ ok,
                                                   u16* __restrict__ ov) {
  const int bid = blockIdx.x;
  const float* in = (bid < 4096) ? q : (bid < 8192 ? k : v);
  u16* out = (bid < 4096) ? oq : (bid < 8192 ? ok : ov);
  const size_t i = ((size_t)(bid & 4095) * 256 + threadIdx.x) * 8;
  const float4* p = (const float4*)(in + i);
  float4 a = p[0], b = p[1];
  u32x4 w;
  w[0] = cvt_pk_bf16(a.x, a.y); w[1] = cvt_pk_bf16(a.z, a.w);
  w[2] = cvt_pk_bf16(b.x, b.y); w[3] = cvt_pk_bf16(b.z, b.w);
  *(u32x4*)(out + i) = w;
}

// ---------- W[K][N] f32 -> Wt[N][K] bf16, 4 weights fused ----------
__global__ __launch_bounds__(256) void wtrans4_kernel(const float* __restrict__ Wq, const float* __restrict__ Wk,
                                                      const float* __restrict__ Wv, const float* __restrict__ Wo,
                                                      u16* __restrict__ WtQ, u16* __restrict__ WtK,
                                                      u16* __restrict__ WtV, u16* __restrict__ WtO) {
  const int bid = blockIdx.x;
  const int wsel = bid >> 9;
  const float* W = (wsel == 0) ? Wq : (wsel == 1) ? Wk : (wsel == 2) ? Wv : Wo;
  u16* Wt = (wsel == 0) ? WtQ : (wsel == 1) ? WtK : (wsel == 2) ? WtV : WtO;
  const int tid = (bid & 511) * 256 + threadIdx.x;
  const int n = tid & 1023;
  const int kb = (tid >> 10) << 3;
  u32x4 w;
#pragma unroll
  for (int j = 0; j < 4; j++)
    w[j] = cvt_pk_bf16(W[(size_t)(kb + 2 * j) * 1024 + n], W[(size_t)(kb + 2 * j + 1) * 1024 + n]);
  *(u32x4*)(Wt + (size_t)n * 1024 + kb) = w;
}

// ---------- 8-phase-style pipelined GEMM ----------
// BM=256, BN=128, BK=32, 4 waves (2Mx2N), wave-tile 128x64 (8mt x 4nt frags).
// 3 LDS buffers (72KB) -> 2 blocks/CU; compute tile T while tile T+2 stages.
// Counted vmcnt(6) at K-tile boundaries (never 0 in main loop), raw s_barrier,
// setprio around MFMA clusters. Chunk-swizzled LDS (same scheme as before).
// IS_QKV=1: A=[qin;kin;vin] 24576 rows, sections by bm>>5 (Q scaled / K / permuted-Vt).
// IS_QKV=0: f32 out + bias.
template <int IS_QKV>
__global__ __launch_bounds__(256, 2) void gemm256_kernel(const u16* __restrict__ A,
                                                         const u16* __restrict__ Wt,
                                                         const float* __restrict__ bQ,
                                                         const float* __restrict__ bK,
                                                         const float* __restrict__ bV,
                                                         void* __restrict__ Outs,
                                                         float qscale) {
  constexpr int K = 1024;
  constexpr int NBM = IS_QKV ? 96 : 32;   // grid = NBM*8 blocks
  constexpr int NT = 32;                  // K / BK
  __shared__ u16 Ash[3][8192];            // 256 x 32 bf16, swizzled, 16KB each
  __shared__ u16 Bsh[3][4096];            // 128 x 32 bf16, swizzled,  8KB each
  const int t = threadIdx.x, l = t & 63, w = t >> 6;
  const int wm = w >> 1, wn = w & 1;
  const int g = l >> 4, ql = l & 15;
  const int bid = blockIdx.x;
  const int s = (bid & 7) * NBM + (bid >> 3);   // XCD-bijective swizzle
  const int bm = s >> 3, bn = s & 7;
  const int m0 = bm * 256, n0 = bn * 128;

  const int sec = IS_QKV ? (bm >> 5) : 0;
  const u16* Bt = Wt + ((size_t)sec << 20);
  const u16* Ab = A + (size_t)m0 * K;
  const u16* Bb = Bt + (size_t)n0 * K;

  f32x4 acc[8][4];
#pragma unroll
  for (int i = 0; i < 8; i++)
#pragma unroll
    for (int j = 0; j < 4; j++) acc[i][j] = (f32x4){0.f, 0.f, 0.f, 0.f};

  // staging map (same chunk swizzle as before, 128B lines = 2 rows of 64B)
  const int slc = (t & 7) ^ ((t >> 3) & 7);
  const int srow = 2 * (t >> 3) + (slc >> 2);
  const int skc = (slc & 3) << 3;

  // fragment read offsets
  int aoff[8], boff[4];
#pragma unroll
  for (int mt = 0; mt < 8; mt++) {
    const int R = wm * 128 + mt * 16 + ql;
    const int cc = (((R & 1) << 2) + g) ^ ((R >> 1) & 7);
    aoff[mt] = (R >> 1) * 64 + cc * 8;
  }
#pragma unroll
  for (int nt = 0; nt < 4; nt++) {
    const int R = wn * 64 + nt * 16 + ql;
    const int cc = (((R & 1) << 2) + g) ^ ((R >> 1) & 7);
    boff[nt] = (R >> 1) * 64 + cc * 8;
  }

  auto stA = [&](int buf, int k0s, int j) {
    gload_lds16(Ab + (size_t)(srow + 64 * j) * K + k0s + skc, &Ash[buf][j * 2048 + w * 512]);
  };
  auto stB = [&](int buf, int k0s, int j) {
    gload_lds16(Bb + (size_t)(srow + 64 * j) * K + k0s + skc, &Bsh[buf][j * 2048 + w * 512]);
  };

  // prologue: stage tiles 0 and 1
#pragma unroll
  for (int j = 0; j < 4; j++) stA(0, 0, j);
  stB(0, 0, 0); stB(0, 0, 1);
#pragma unroll
  for (int j = 0; j < 4; j++) stA(1, 32, j);
  stB(1, 32, 0); stB(1, 32, 1);
  asm volatile("s_waitcnt vmcnt(6)" ::: "memory");
  __builtin_amdgcn_sched_barrier(0);
  __builtin_amdgcn_s_barrier();

  int cur = 0;
  for (int T = 0; T < NT; ++T) {
    const int stg = (cur >= 1) ? cur - 1 : cur + 2;   // (cur+2)%3
    const bool doStage = (T + 2 < NT);
    const int k0s = T * 32 + 64;
    const u16* AC = Ash[cur];
    const u16* BC = Bsh[cur];

    // ---- phase 0: frags mt 0..3, stage A0,A1,B0 of tile T+2 ----
    short8 af[4], bf[4];
#pragma unroll
    for (int i = 0; i < 4; i++) af[i] = *(const short8*)&AC[aoff[i]];
#pragma unroll
    for (int i = 0; i < 4; i++) bf[i] = *(const short8*)&BC[boff[i]];
    if (doStage) { stA(stg, k0s, 0); stA(stg, k0s, 1); stB(stg, k0s, 0); }
    __builtin_amdgcn_s_barrier();
    __builtin_amdgcn_s_setprio(1);
#pragma unroll
    for (int i = 0; i < 4; i++)
#pragma unroll
      for (int nt = 0; nt < 4; nt++)
        acc[i][nt] = mfma16(af[i], bf[nt], acc[i][nt]);
    __builtin_amdgcn_s_setprio(0);
    __builtin_amdgcn_s_barrier();

    // ---- phase 1: frags mt 4..7, stage A2,A3,B1 of tile T+2 ----
    short8 ag[4];
#pragma unroll
    for (int i = 0; i < 4; i++) ag[i] = *(const short8*)&AC[aoff[4 + i]];
    if (doStage) { stA(stg, k0s, 2); stA(stg, k0s, 3); stB(stg, k0s, 1); }
    __builtin_amdgcn_s_barrier();
    __builtin_amdgcn_s_setprio(1);
#pragma unroll
    for (int i = 0; i < 4; i++)
#pragma unroll
      for (int nt = 0; nt < 4; nt++)
        acc[4 + i][nt] = mfma16(ag[i], bf[nt], acc[4 + i][nt]);
    __builtin_amdgcn_s_setprio(0);
    if (T < NT - 2) {
      asm volatile("s_waitcnt vmcnt(6)" ::: "memory");
      __builtin_amdgcn_sched_barrier(0);
    } else if (T == NT - 2) {
      asm volatile("s_waitcnt vmcnt(0)" ::: "memory");
      __builtin_amdgcn_sched_barrier(0);
    }
    __builtin_amdgcn_s_barrier();
    cur = (cur == 2) ? 0 : cur + 1;
  }

  // ---- epilogue ----
  if constexpr (IS_QKV) {
    const float* bias = (sec == 0) ? bQ : (sec == 1) ? bK : bV;
    const float outscale = (sec == 0) ? qscale : 1.0f;
    const int mloc = m0 & 8191;
#pragma unroll
    for (int nt = 0; nt < 4; nt++) {
      const int n = n0 + wn * 64 + nt * 16 + ql;
      const float bv2 = bias[n];
      if (sec < 2) {
        u16* C = (u16*)Outs + ((size_t)sec << 23);
#pragma unroll
        for (int mt = 0; mt < 8; mt++) {
          const int m = mloc + wm * 128 + mt * 16 + (g << 2);
#pragma unroll
          for (int r = 0; r < 4; r++)
            C[(size_t)(m + r) * 1024 + n] = f2bf((acc[mt][nt][r] + bv2) * outscale);
        }
      } else {
        const int b2 = mloc >> 11;
        const int h2 = n >> 6, d = n & 63;
        u16* C = (u16*)Outs + ((size_t)2 << 23);
#pragma unroll
        for (int mt = 0; mt < 8; mt++) {
          const int s0 = (mloc & 2047) + wm * 128 + mt * 16 + (g << 2);
          const int u = s0 & 63;
          // kk-permutation: pos = (gg + 4*(c2>>1))*8 + (c2&1)*4 + j
          const int pos = ((((u >> 2) & 3) + ((u >> 5) & 1) * 4) << 3) + ((u >> 4) & 1) * 4;
          const int sp = (s0 & ~63) + pos;
          ushort4 pk;
          pk.x = f2bf(acc[mt][nt][0] + bv2);
          pk.y = f2bf(acc[mt][nt][1] + bv2);
          pk.z = f2bf(acc[mt][nt][2] + bv2);
          pk.w = f2bf(acc[mt][nt][3] + bv2);
          *(ushort4*)(C + (((size_t)((b2 * 16 + h2) * 64 + d)) << 11) + sp) = pk;
        }
      }
    }
  } else {
    float* C = (float*)Outs;
#pragma unroll
    for (int nt = 0; nt < 4; nt++) {
      const int n = n0 + wn * 64 + nt * 16 + ql;
      const float bv2 = bQ[n];
#pragma unroll
      for (int mt = 0; mt < 8; mt++) {
        const int m = m0 + wm * 128 + mt * 16 + (g << 2);
#pragma unroll
        for (int r = 0; r < 4; r++)
          C[(size_t)(m + r) * 1024 + n] = acc[mt][nt][r] + bv2;
      }
    }
  }
}

// ---------- no-max softmax for one 16-q half ----------
__device__ __forceinline__ void softmax_lite(const f32x4 (&s)[4], float& lsum,
                                             short8& pa0, short8& pa1) {
  float p[4][4];
#pragma unroll
  for (int c = 0; c < 4; c++)
#pragma unroll
    for (int r = 0; r < 4; r++) p[c][r] = __builtin_amdgcn_exp2f(s[c][r]);
  lsum += (((p[0][0] + p[0][1]) + (p[0][2] + p[0][3])) + ((p[1][0] + p[1][1]) + (p[1][2] + p[1][3])))
        + (((p[2][0] + p[2][1]) + (p[2][2] + p[2][3])) + ((p[3][0] + p[3][1]) + (p[3][2] + p[3][3])));
  V8 u0, u1;
  u0.u[0] = cvt_pk_bf16(p[0][0], p[0][1]); u0.u[1] = cvt_pk_bf16(p[0][2], p[0][3]);
  u0.u[2] = cvt_pk_bf16(p[1][0], p[1][1]); u0.u[3] = cvt_pk_bf16(p[1][2], p[1][3]);
  u1.u[0] = cvt_pk_bf16(p[2][0], p[2][1]); u1.u[1] = cvt_pk_bf16(p[2][2], p[2][3]);
  u1.u[2] = cvt_pk_bf16(p[3][0], p[3][1]); u1.u[3] = cvt_pk_bf16(p[3][2], p[3][3]);
  pa0 = u0.s; pa1 = u1.s;
}

// ---------- flash attention (no-max, permuted-V) ----------
__global__ __launch_bounds__(256) void attn_kernel(const u16* __restrict__ Qb,
                                                   const u16* __restrict__ Kb,
                                                   const u16* __restrict__ Vtb,
                                                   u16* __restrict__ AO) {
  __shared__ u16 Ksh[2][4096];   // [64 kk][64 d], chunk-swizzled
  __shared__ u16 Vsh[2][4096];   // [64 d][64 kk-permuted], chunk-swizzled
  const int t = threadIdx.x, l = t & 63, w = t >> 6;
  const int g = l >> 4, ql = l & 15;
  const int bid0 = blockIdx.x;
  const int bid = (bid0 & 7) * 128 + (bid0 >> 3);   // XCD swizzle
  const int qt = bid & 15;
  const int bh = bid >> 4;
  const int h = bh & 15, b = bh >> 4;
  const int q0 = qt * 128 + w * 32;

  const u16* Qrow = Qb + ((size_t)b * 2048 + q0 + ql) * 1024 + h * 64 + g * 8;
  const short8 qA0 = *(const short8*)(Qrow);
  const short8 qA1 = *(const short8*)(Qrow + 32);
  const short8 qB0 = *(const short8*)(Qrow + 16 * 1024);
  const short8 qB1 = *(const short8*)(Qrow + 16 * 1024 + 32);

  float lA = 0.f, lB = 0.f;
  f32x4 oA[4], oB[4];
#pragma unroll
  for (int i = 0; i < 4; i++) { oA[i] = (f32x4){0.f, 0.f, 0.f, 0.f}; oB[i] = oA[i]; }

  const int srow0 = t >> 3, sc = t & 7;
  const int slc0 = sc ^ (srow0 & 7);
  const int srow1 = srow0 + 32, slc1 = sc ^ (srow1 & 7);
  const u16* Kbase = Kb + ((size_t)b * 2048) * 1024 + h * 64;
  const u16* Vbase = Vtb + ((size_t)(b * 16 + h) * 64) * 2048;

  auto stage = [&](int buf, int kk0) {
    u16* KW = &Ksh[buf][w * 512];
    u16* VW = &Vsh[buf][w * 512];
    gload_lds16(Kbase + (size_t)(kk0 + srow0) * 1024 + slc0 * 8, KW);
    gload_lds16(Kbase + (size_t)(kk0 + srow1) * 1024 + slc1 * 8, KW + 2048);
    gload_lds16(Vbase + (size_t)srow0 * 2048 + kk0 + slc0 * 8, VW);
    gload_lds16(Vbase + (size_t)srow1 * 2048 + kk0 + slc1 * 8, VW + 2048);
  };

  int voff0[4], voff1[4];
#pragma unroll
  for (int dt = 0; dt < 4; dt++) {
    const int d = dt * 16 + ql;
    voff0[dt] = d * 64 + ((g ^ (d & 7)) << 3);
    voff1[dt] = d * 64 + (((g + 4) ^ (d & 7)) << 3);
  }

  stage(0, 0);
  __syncthreads();
  int cur = 0;

  for (int kk0 = 0; kk0 < 2048; kk0 += 64) {
    if (kk0 + 64 < 2048) stage(cur ^ 1, kk0 + 64);
    const u16* KC = Ksh[cur];
    const u16* VC = Vsh[cur];

    f32x4 sA[4], sB[4];
    __builtin_amdgcn_s_setprio(1);
#pragma unroll
    for (int c = 0; c < 4; c++) {
      const int R = c * 16 + ql;
      const int x = R & 7;
      const short8 kf0 = *(const short8*)&KC[R * 64 + ((g ^ x) << 3)];
      const short8 kf1 = *(const short8*)&KC[R * 64 + (((g + 4) ^ x) << 3)];
      f32x4 z = (f32x4){0.f, 0.f, 0.f, 0.f};
      z = mfma16(kf0, qA0, z);
      sA[c] = mfma16(kf1, qA1, z);
      z = (f32x4){0.f, 0.f, 0.f, 0.f};
      z = mfma16(kf0, qB0, z);
      sB[c] = mfma16(kf1, qB1, z);
    }
    __builtin_amdgcn_s_setprio(0);

    short8 paA0, paA1, paB0, paB1;
    softmax_lite(sA, lA, paA0, paA1);
    softmax_lite(sB, lB, paB0, paB1);

    __builtin_amdgcn_s_setprio(1);
#pragma unroll
    for (int dt = 0; dt < 4; dt++) {
      const short8 vf0 = *(const short8*)&VC[voff0[dt]];
      const short8 vf1 = *(const short8*)&VC[voff1[dt]];
      oA[dt] = mfma16(paA0, vf0, oA[dt]);
      oA[dt] = mfma16(paA1, vf1, oA[dt]);
      oB[dt] = mfma16(paB0, vf0, oB[dt]);
      oB[dt] = mfma16(paB1, vf1, oB[dt]);
    }
    __builtin_amdgcn_s_setprio(0);
    __syncthreads();
    cur ^= 1;
  }

  lA += __shfl_xor(lA, 16); lA += __shfl_xor(lA, 32);
  lB += __shfl_xor(lB, 16); lB += __shfl_xor(lB, 32);
  const float iA = __builtin_amdgcn_rcpf(lA);
  const float iB = __builtin_amdgcn_rcpf(lB);
  const int sb = g << 2;
  const float iA0 = __shfl(iA, sb), iA1 = __shfl(iA, sb + 1);
  const float iA2 = __shfl(iA, sb + 2), iA3 = __shfl(iA, sb + 3);
  const float iB0 = __shfl(iB, sb), iB1 = __shfl(iB, sb + 1);
  const float iB2 = __shfl(iB, sb + 2), iB3 = __shfl(iB, sb + 3);
  u16* Arow = AO + ((size_t)b * 2048 + q0) * 1024 + h * 64;
#pragma unroll
  for (int dt = 0; dt < 4; dt++) {
    const int col = dt * 16 + ql;
    Arow[(size_t)(4 * g + 0) * 1024 + col] = f2bf(oA[dt][0] * iA0);
    Arow[(size_t)(4 * g + 1) * 1024 + col] = f2bf(oA[dt][1] * iA1);
    Arow[(size_t)(4 * g + 2) * 1024 + col] = f2bf(oA[dt][2] * iA2);
    Arow[(size_t)(4 * g + 3) * 1024 + col] = f2bf(oA[dt][3] * iA3);
    Arow[(size_t)(16 + 4 * g + 0) * 1024 + col] = f2bf(oB[dt][0] * iB0);
    Arow[(size_t)(16 + 4 * g + 1) * 1024 + col] = f2bf(oB[dt][1] * iB1);
    Arow[(size_t)(16 + 4 * g + 2) * 1024 + col] = f2bf(oB[dt][2] * iB2);
    Arow[(size_t)(16 + 4 * g + 3) * 1024 + col] = f2bf(oB[dt][3] * iB3);
  }
}

// ---------- launch ----------
extern "C" void kernel_launch(void* const* d_in, const int* in_sizes, int n_in,
                              void* d_out, int out_size, void* d_ws, size_t ws_size,
                              hipStream_t stream) {
  (void)in_sizes; (void)n_in; (void)out_size; (void)ws_size;
  const float* query = (const float*)d_in[0];
  const float* key   = (const float*)d_in[1];
  const float* value = (const float*)d_in[2];
  const float* Wq = (const float*)d_in[3];  const float* bq = (const float*)d_in[4];
  const float* Wk = (const float*)d_in[5];  const float* bk = (const float*)d_in[6];
  const float* Wv = (const float*)d_in[7];  const float* bv = (const float*)d_in[8];
  const float* Wo = (const float*)d_in[9];  const float* bo = (const float*)d_in[10];
  float* out = (float*)d_out;

  const size_t SZX = (size_t)8192 * 1024;
  const size_t SZW = (size_t)1024 * 1024;
  u16* qin = (u16*)d_ws;          // A-stack base: [qin;kin;vin]
  u16* kin = qin + SZX;
  u16* vin = kin + SZX;
  u16* Qb  = vin + SZX;           // outputs: [Qb;Kbf;Vtb] consecutive
  u16* Kbf = Qb + SZX;
  u16* Vtb = Kbf + SZX;
  u16* WtQ = Vtb + SZX;           // weights: [WtQ;WtK;WtV;WtO] consecutive
  u16* WtK = WtQ + SZW;
  u16* WtV = WtK + SZW;
  u16* WtO = WtV + SZW;
  u16* AO  = qin;                 // reuse (dead after QKV GEMM)

  const float QSCALE = 0.125f * 1.44269504088896f;   // 1/sqrt(64) * log2(e) folded into Q

  cvt3_kernel<<<12288, 256, 0, stream>>>(query, key, value, qin, kin, vin);
  wtrans4_kernel<<<2048, 256, 0, stream>>>(Wq, Wk, Wv, Wo, WtQ, WtK, WtV, WtO);

  gemm256_kernel<1><<<768, 256, 0, stream>>>(qin, WtQ, bq, bk, bv, (void*)Qb, QSCALE);

  attn_kernel<<<1024, 256, 0, stream>>>(Qb, Kbf, Vtb, AO);

  gemm256_kernel<0><<<256, 256, 0, stream>>>(AO, WtO, bo, bo, bo, (void*)out, 1.0f);
}